// Round 3
// baseline (239.743 us; speedup 1.0000x reference)
//
#include <hip/hip_runtime.h>

#define C_CH  256
#define H_FM  200
#define W_FM  200
#define N_BOX 1024
#define OHp   7
#define OWp   7
#define WC    (W_FM * C_CH)          // 51200 floats per h-row of T
#define NCHUNK 25                    // h chunks of 8 rows
#define CHROWS 8

// ============================================================================
// K1: transpose + FULL w-scan in one pass.
// Block = (one h, c-tile of 32). Thread (c_off, ch) streams 25 consecutive
// w values of its channel row, prefix-summing in registers (no cross-lane
// scan). Chunk totals get an 8-wide exclusive scan in LDS; offsets are added
// during the transposed coalesced write to T[h][w][c].
// ============================================================================
__global__ __launch_bounds__(256) void transpose_wscan_kernel(const float* __restrict__ fm,
                                                              float* __restrict__ T) {
    __shared__ float tile[W_FM][33];   // [w][c_off], 33 kills bank conflicts
    __shared__ float tot[8][33];       // chunk inclusive totals
    __shared__ float offE[8][33];      // chunk exclusive offsets
    const int t     = threadIdx.x;
    const int h     = blockIdx.x;
    const int c0    = blockIdx.y * 32;
    const int c_off = t & 31;
    const int ch    = t >> 5;          // 0..7, chunk of 25 w values

    const float* src = fm + (size_t)(c0 + c_off) * (H_FM * W_FM)
                          + (size_t)h * W_FM + ch * 25;
    float acc = 0.0f;
    #pragma unroll
    for (int s = 0; s < 25; ++s) {
        acc += src[s];
        tile[ch * 25 + s][c_off] = acc;
    }
    tot[ch][c_off] = acc;
    __syncthreads();

    // exclusive scan of the 8 chunk totals for this c_off (all lanes read all
    // 8 values -> broadcast-ish, conflict-free)
    float off = 0.0f;
    #pragma unroll
    for (int k = 0; k < 8; ++k) {
        float v = tot[k][c_off];
        if (k < ch) off += v;
    }
    offE[ch][c_off] = off;
    __syncthreads();

    // transposed write-out, adding the chunk offset: T[h][w][c0+cc]
    float* dst = T + (size_t)h * WC + c0;
    #pragma unroll
    for (int m = 0; m < 25; ++m) {
        int flat = m * 256 + t;        // 0..6399
        int w  = flat >> 5;            // 0..199
        int cc = flat & 31;
        dst[(size_t)w * C_CH + cc] = tile[w][cc] + offE[w / 25][cc];
    }
}

// ============================================================================
// K2: column cumsum over h, per chunk of 8 rows, in place on T[h][w][c].
// Fully coalesced. Writes chunk totals to aux[ch][w][c].
// ============================================================================
__global__ __launch_bounds__(256) void colscan_chunk_kernel(float* __restrict__ T,
                                                            float* __restrict__ aux) {
    const int wc = blockIdx.x * 256 + threadIdx.x;   // 0..WC-1
    const int ch = blockIdx.y;                        // 0..NCHUNK-1
    float* p = T + (size_t)(ch * CHROWS) * WC + wc;
    float acc = 0.0f;
    #pragma unroll
    for (int k = 0; k < CHROWS; ++k) {
        acc += p[(size_t)k * WC];
        p[(size_t)k * WC] = acc;
    }
    aux[(size_t)ch * WC + wc] = acc;
}

// ============================================================================
// K3: exclusive scan of chunk totals over the 25 chunks, in place.
// ============================================================================
__global__ __launch_bounds__(256) void aux_scan_kernel(float* __restrict__ aux) {
    const int wc = blockIdx.x * 256 + threadIdx.x;
    float acc = 0.0f;
    #pragma unroll
    for (int ch = 0; ch < NCHUNK; ++ch) {
        float v = aux[(size_t)ch * WC + wc];
        aux[(size_t)ch * WC + wc] = acc;
        acc += v;
    }
}

// ============================================================================
// K4: pooling with the h-chunk offset folded in on the fly:
//   II(r,k)[c] = T[(r-1)][(k-1)][c] + auxS[(r-1)>>3][(k-1)][c]   (r,k >= 1)
// Block = one box, thread = one channel; every read is a coalesced 1 KB
// transaction. Output staged in LDS, flushed coalesced.
// ============================================================================
__global__ __launch_bounds__(256) void pool3_kernel(const float* __restrict__ T,
                                                    const float* __restrict__ auxS,
                                                    const float* __restrict__ boxes,
                                                    float* __restrict__ out) {
    __shared__ float lo[256 * 50];   // [c][49] padded to 50
    const int n = blockIdx.x;
    const int c = threadIdx.x;

    const float4 box = ((const float4*)boxes)[n];
    int b0 = (int)floorf(box.x * 0.25f);
    int b1 = (int)floorf(box.y * 0.25f);
    int b2 = (int)floorf(box.z * 0.25f);
    int b3 = (int)floorf(box.w * 0.25f);
    int x1 = min(max(b0, 0), W_FM - 1);
    int y1 = min(max(b1, 0), H_FM - 1);
    int x2 = min(max(b2 + 1, x1 + 1), W_FM);
    int y2 = min(max(b3 + 1, y1 + 1), H_FM);
    int rh = y2 - y1;
    int rw = x2 - x1;

    int rs[OHp], re[OHp], cols[2 * OWp];
    #pragma unroll
    for (int i = 0; i < OHp; ++i) {
        rs[i] = y1 + (i * rh) / OHp;
        re[i] = y1 + ((i + 1) * rh + OHp - 1) / OHp;
    }
    #pragma unroll
    for (int j = 0; j < OWp; ++j) {
        cols[j]       = x1 + (j * rw) / OWp;
        cols[OWp + j] = x1 + ((j + 1) * rw + OWp - 1) / OWp;
    }

    const float* Tc = T + c;
    const float* Ac = auxS + c;
    #pragma unroll
    for (int i = 0; i < OHp; ++i) {
        float top[2 * OWp], bot[2 * OWp];
        const int rt = rs[i], rb = re[i];
        const size_t tRow = (size_t)(rt - 1) * W_FM;
        const size_t bRow = (size_t)(rb - 1) * W_FM;
        const size_t tAux = (size_t)((rt - 1) >> 3) * W_FM;
        const size_t bAux = (size_t)((rb - 1) >> 3) * W_FM;
        #pragma unroll
        for (int k = 0; k < 2 * OWp; ++k) {
            const int kk = cols[k];
            // block-uniform conditions -> no divergence
            top[k] = (rt > 0 && kk > 0)
                   ? Tc[(tRow + (kk - 1)) * C_CH] + Ac[(tAux + (kk - 1)) * C_CH]
                   : 0.0f;
            bot[k] = (kk > 0)
                   ? Tc[(bRow + (kk - 1)) * C_CH] + Ac[(bAux + (kk - 1)) * C_CH]
                   : 0.0f;
        }
        const float rowspan = (float)(rb - rt);
        #pragma unroll
        for (int j = 0; j < OWp; ++j) {
            float total = (bot[OWp + j] - bot[j]) - (top[OWp + j] - top[j]);
            float area  = rowspan * (float)(cols[OWp + j] - cols[j]);
            lo[c * 50 + i * OWp + j] = total / area;
        }
    }
    __syncthreads();

    // Coalesced flush: out[n][c][i][j], flat = c*49 + i*7 + j
    float* dst = out + (size_t)n * (C_CH * OHp * OWp);
    #pragma unroll 7
    for (int m = 0; m < 49; ++m) {
        int flat = m * 256 + c;
        int cc = flat / 49;
        int ii = flat - cc * 49;
        dst[flat] = lo[cc * 50 + ii];
    }
}

// ============================================================================
// FALLBACK PATH — used only if workspace is too small.
// ============================================================================
__device__ __forceinline__ void box_edges(const float4 box, int i, int j,
                                          int& rs, int& re, int& cs, int& ce) {
    int b0 = (int)floorf(box.x * 0.25f);
    int b1 = (int)floorf(box.y * 0.25f);
    int b2 = (int)floorf(box.z * 0.25f);
    int b3 = (int)floorf(box.w * 0.25f);
    int x1 = min(max(b0, 0), W_FM - 1);
    int y1 = min(max(b1, 0), H_FM - 1);
    int x2 = min(max(b2 + 1, x1 + 1), W_FM);
    int y2 = min(max(b3 + 1, y1 + 1), H_FM);
    int rh = y2 - y1;
    int rw = x2 - x1;
    rs = y1 + (i * rh) / OHp;
    re = y1 + ((i + 1) * rh + OHp - 1) / OHp;
    cs = x1 + (j * rw) / OWp;
    ce = x1 + ((j + 1) * rw + OWp - 1) / OWp;
}

__global__ __launch_bounds__(256) void pool_direct_kernel(const float* __restrict__ fm,
                                                          const float* __restrict__ boxes,
                                                          float* __restrict__ out) {
    const int idx = blockIdx.x * 256 + threadIdx.x;
    const int j  = idx % OWp;
    const int t1 = idx / OWp;
    const int i  = t1 % OHp;
    const int t2 = t1 / OHp;
    const int c  = t2 % C_CH;
    const int n  = t2 / C_CH;

    const float4 box = ((const float4*)boxes)[n];
    int rs, re, cs, ce;
    box_edges(box, i, j, rs, re, cs, ce);

    const float* base = fm + (size_t)c * (H_FM * W_FM);
    float sum = 0.0f;
    for (int r = rs; r < re; ++r) {
        const float* rowp = base + (size_t)r * W_FM;
        for (int k = cs; k < ce; ++k) sum += rowp[k];
    }
    float area = (float)((re - rs) * (ce - cs));
    out[idx] = sum / area;
}

// ---------------------------------------------------------------------------
extern "C" void kernel_launch(void* const* d_in, const int* in_sizes, int n_in,
                              void* d_out, int out_size, void* d_ws, size_t ws_size,
                              hipStream_t stream) {
    const float* fm    = (const float*)d_in[0];   // [1,256,200,200] f32
    const float* boxes = (const float*)d_in[1];   // [1024,4] f32
    float* out = (float*)d_out;                   // [1024,256,7,7] f32

    const size_t tBytes   = (size_t)H_FM * WC * sizeof(float);        // 40.96 MB
    const size_t auxBytes = (size_t)NCHUNK * WC * sizeof(float);      // 5.12 MB
    const int    total    = N_BOX * C_CH * OHp * OWp;
    const int    blocks   = total / 256;

    if (ws_size >= tBytes + auxBytes) {
        float* T   = (float*)d_ws;
        float* aux = (float*)((char*)d_ws + tBytes);
        transpose_wscan_kernel<<<dim3(H_FM, C_CH / 32), 256, 0, stream>>>(fm, T);
        colscan_chunk_kernel<<<dim3(WC / 256, NCHUNK), 256, 0, stream>>>(T, aux);
        aux_scan_kernel<<<WC / 256, 256, 0, stream>>>(aux);
        pool3_kernel<<<N_BOX, 256, 0, stream>>>(T, aux, boxes, out);
    } else {
        pool_direct_kernel<<<blocks, 256, 0, stream>>>(fm, boxes, out);
    }
}

// Round 4
// 145.139 us; speedup vs baseline: 1.6518x; 1.6518x over previous
//
#include <hip/hip_runtime.h>

#define C_CH  256
#define H_FM  200
#define W_FM  200
#define N_BOX 1024
#define OHp   7
#define OWp   7
#define NG    8                       // channel groups
#define CG    32                      // channels per group
#define WC    (W_FM * C_CH)           // 51200 columns
#define NCHUNK 25                     // h chunks of 8 rows
#define CHROWS 8
#define GSTRIDE (H_FM * W_FM * CG)    // 1,280,000 floats per group slice
#define HSTRIDE (W_FM * CG)           // 6,400 floats per h row (within group)

// ============================================================================
// T2 layout: T2[g][h][w][cg], channel-group-major. Group g holds channels
// [32g, 32g+32). This makes pool's per-XCD working set one 5.1 MB slice.
// ============================================================================

// ----------------------------------------------------------------------------
// K1: coalesced load -> LDS -> register-serial w-scan -> coalesced transposed
// store into T2 (full w-prefix, h not yet scanned).
// Block = (h, group g). 256 threads.
// ----------------------------------------------------------------------------
__global__ __launch_bounds__(256) void transpose_wscan_kernel(const float* __restrict__ fm,
                                                              float* __restrict__ T2) {
    __shared__ float tile[W_FM][CG + 1];   // [w][cg], +1 pad
    __shared__ float tot[8][CG + 1];
    __shared__ float offE[8][CG + 1];
    const int t = threadIdx.x;
    const int h = blockIdx.x;
    const int g = blockIdx.y;
    const int c0 = g * CG;

    // Coalesced load: 32 channel-rows x 200 w = 6400 floats.
    #pragma unroll
    for (int s = 0; s < 25; ++s) {
        int flat = s * 256 + t;            // 0..6399
        int ci = flat / W_FM;
        int w  = flat - ci * W_FM;
        tile[w][ci] = fm[(size_t)(c0 + ci) * (H_FM * W_FM) + (size_t)h * W_FM + w];
    }
    __syncthreads();

    // Register-serial scan: thread (cg, chb) scans w in [chb*25, chb*25+25).
    const int cg  = t & 31;
    const int chb = t >> 5;                // 0..7
    {
        float acc = 0.0f;
        #pragma unroll
        for (int s = 0; s < 25; ++s) {
            acc += tile[chb * 25 + s][cg];
            tile[chb * 25 + s][cg] = acc;
        }
        tot[chb][cg] = acc;
    }
    __syncthreads();

    // Exclusive scan of the 8 w-chunk totals.
    {
        float off = 0.0f;
        #pragma unroll
        for (int k = 0; k < 8; ++k) {
            float v = tot[k][cg];
            if (k < chb) off += v;
        }
        offE[chb][cg] = off;
    }
    __syncthreads();

    // Coalesced store: T2[g][h][w][cg], contiguous 6400-float run.
    float* dst = T2 + (size_t)g * GSTRIDE + (size_t)h * HSTRIDE;
    #pragma unroll
    for (int m = 0; m < 25; ++m) {
        int flat = m * 256 + t;
        int w  = flat >> 5;
        int cc = flat & 31;
        dst[flat] = tile[w][cc] + offE[w / 25][cc];
    }
}

// ----------------------------------------------------------------------------
// K2: h-cumsum per chunk of 8 rows, in place. Column space: col = g*6400 + q
// (q = w*32+cg), stride per h = HSTRIDE. Writes chunk totals to aux[ch][col].
// Grid (WC/256=200, NCHUNK). Fully coalesced.
// ----------------------------------------------------------------------------
__global__ __launch_bounds__(256) void colscan_chunk_kernel(float* __restrict__ T2,
                                                            float* __restrict__ aux) {
    const int col = blockIdx.x * 256 + threadIdx.x;   // 0..WC-1
    const int ch  = blockIdx.y;
    const int g   = col / HSTRIDE;                    // block spans one g
    const int q   = col - g * HSTRIDE;
    float* p = T2 + (size_t)g * GSTRIDE + (size_t)(ch * CHROWS) * HSTRIDE + q;
    float acc = 0.0f;
    #pragma unroll
    for (int k = 0; k < CHROWS; ++k) {
        acc += p[(size_t)k * HSTRIDE];
        p[(size_t)k * HSTRIDE] = acc;
    }
    aux[(size_t)ch * WC + col] = acc;
}

// ----------------------------------------------------------------------------
// K3: exclusive scan of the 25 chunk totals, in place.
// ----------------------------------------------------------------------------
__global__ __launch_bounds__(256) void aux_scan_kernel(float* __restrict__ aux) {
    const int col = blockIdx.x * 256 + threadIdx.x;
    float acc = 0.0f;
    #pragma unroll
    for (int ch = 0; ch < NCHUNK; ++ch) {
        float v = aux[(size_t)ch * WC + col];
        aux[(size_t)ch * WC + col] = acc;
        acc += v;
    }
}

// ----------------------------------------------------------------------------
// K4: T2 += chunk offsets (finalize), float4, skipping chunk 0 (h<8).
// id covers (h in [8,200)) x (12800 float4 per h-plane across all g).
// ----------------------------------------------------------------------------
__global__ __launch_bounds__(256) void add_offsets_kernel(float* __restrict__ T2,
                                                          const float* __restrict__ aux) {
    const int id = blockIdx.x * 256 + threadIdx.x;    // 0 .. 192*12800-1
    const int hh = id / (WC / 4);
    const int c4 = id - hh * (WC / 4);                // float4 col index
    const int h  = hh + CHROWS;
    const int g  = c4 / (HSTRIDE / 4);
    const int q4 = c4 - g * (HSTRIDE / 4);
    const float4 o = ((const float4*)aux)[(size_t)(h >> 3) * (WC / 4) + c4];
    float4* tp = (float4*)T2 + (size_t)g * (GSTRIDE / 4) + (size_t)h * (HSTRIDE / 4) + q4;
    float4 v = *tp;
    v.x += o.x; v.y += o.y; v.z += o.z; v.w += o.w;
    *tp = v;
}

// ----------------------------------------------------------------------------
// K5: pooling. Block = (box n, group g), blockIdx = n*8+g so XCD (= blockIdx%8
// heuristic) g only touches its own 5.1 MB T2 slice. Thread (cg, islot):
// islot<7 computes output row i=islot for channel 32g+cg: 28 corner loads
// (128 B coalesced segments per 32 lanes), 7 outputs. LDS = 6.3 KB ->
// ~8 blocks/CU. Output staged in LDS, flushed as one contiguous 1568-float
// coalesced run.
// ----------------------------------------------------------------------------
__global__ __launch_bounds__(256) void pool4_kernel(const float* __restrict__ T2,
                                                    const float* __restrict__ boxes,
                                                    float* __restrict__ out) {
    __shared__ float lo[CG * 49];     // flat == output chunk layout [cg][49]
    const int bx = blockIdx.x;
    const int n  = bx >> 3;
    const int g  = bx & 7;
    const int t  = threadIdx.x;
    const int cg = t & 31;
    const int islot = t >> 5;         // 0..7 (7 idle)

    const float4 box = ((const float4*)boxes)[n];
    int b0 = (int)floorf(box.x * 0.25f);
    int b1 = (int)floorf(box.y * 0.25f);
    int b2 = (int)floorf(box.z * 0.25f);
    int b3 = (int)floorf(box.w * 0.25f);
    int x1 = min(max(b0, 0), W_FM - 1);
    int y1 = min(max(b1, 0), H_FM - 1);
    int x2 = min(max(b2 + 1, x1 + 1), W_FM);
    int y2 = min(max(b3 + 1, y1 + 1), H_FM);
    int rh = y2 - y1;
    int rw = x2 - x1;

    if (islot < OHp) {
        const int i  = islot;
        const int rt = y1 + (i * rh) / OHp;
        const int rb = y1 + ((i + 1) * rh + OHp - 1) / OHp;
        int colv[2 * OWp];
        #pragma unroll
        for (int j = 0; j < OWp; ++j) {
            colv[j]       = x1 + (j * rw) / OWp;
            colv[OWp + j] = x1 + ((j + 1) * rw + OWp - 1) / OWp;
        }
        const float* base = T2 + (size_t)g * GSTRIDE + cg;
        const int ra = max(rt - 1, 0) * W_FM;
        const int rbm = (rb - 1) * W_FM;              // rb >= 1 always
        float top[2 * OWp], bot[2 * OWp];
        #pragma unroll
        for (int k = 0; k < 2 * OWp; ++k) {
            const int kk = colv[k];
            const int ka = max(kk - 1, 0);
            float tv = base[(size_t)(ra  + ka) * CG];
            float bv = base[(size_t)(rbm + ka) * CG];
            top[k] = (rt > 0 && kk > 0) ? tv : 0.0f;
            bot[k] = (kk > 0)           ? bv : 0.0f;
        }
        const float rowspan = (float)(rb - rt);
        #pragma unroll
        for (int j = 0; j < OWp; ++j) {
            float total = (bot[OWp + j] - bot[j]) - (top[OWp + j] - top[j]);
            float area  = rowspan * (float)(colv[OWp + j] - colv[j]);
            lo[cg * 49 + i * OWp + j] = total / area;
        }
    }
    __syncthreads();

    // Coalesced flush: out[n][32g..32g+32)[i][j] = 1568 contiguous floats.
    float* dst = out + (size_t)n * (C_CH * 49) + (size_t)g * (CG * 49);
    #pragma unroll
    for (int m = 0; m < 7; ++m) {
        int flat = m * 256 + t;
        if (flat < CG * 49) dst[flat] = lo[flat];
    }
}

// ============================================================================
// FALLBACK PATH — used only if workspace is too small.
// ============================================================================
__device__ __forceinline__ void box_edges(const float4 box, int i, int j,
                                          int& rs, int& re, int& cs, int& ce) {
    int b0 = (int)floorf(box.x * 0.25f);
    int b1 = (int)floorf(box.y * 0.25f);
    int b2 = (int)floorf(box.z * 0.25f);
    int b3 = (int)floorf(box.w * 0.25f);
    int x1 = min(max(b0, 0), W_FM - 1);
    int y1 = min(max(b1, 0), H_FM - 1);
    int x2 = min(max(b2 + 1, x1 + 1), W_FM);
    int y2 = min(max(b3 + 1, y1 + 1), H_FM);
    int rh = y2 - y1;
    int rw = x2 - x1;
    rs = y1 + (i * rh) / OHp;
    re = y1 + ((i + 1) * rh + OHp - 1) / OHp;
    cs = x1 + (j * rw) / OWp;
    ce = x1 + ((j + 1) * rw + OWp - 1) / OWp;
}

__global__ __launch_bounds__(256) void pool_direct_kernel(const float* __restrict__ fm,
                                                          const float* __restrict__ boxes,
                                                          float* __restrict__ out) {
    const int idx = blockIdx.x * 256 + threadIdx.x;
    const int j  = idx % OWp;
    const int t1 = idx / OWp;
    const int i  = t1 % OHp;
    const int t2 = t1 / OHp;
    const int c  = t2 % C_CH;
    const int n  = t2 / C_CH;

    const float4 box = ((const float4*)boxes)[n];
    int rs, re, cs, ce;
    box_edges(box, i, j, rs, re, cs, ce);

    const float* base = fm + (size_t)c * (H_FM * W_FM);
    float sum = 0.0f;
    for (int r = rs; r < re; ++r) {
        const float* rowp = base + (size_t)r * W_FM;
        for (int k = cs; k < ce; ++k) sum += rowp[k];
    }
    float area = (float)((re - rs) * (ce - cs));
    out[idx] = sum / area;
}

// ---------------------------------------------------------------------------
extern "C" void kernel_launch(void* const* d_in, const int* in_sizes, int n_in,
                              void* d_out, int out_size, void* d_ws, size_t ws_size,
                              hipStream_t stream) {
    const float* fm    = (const float*)d_in[0];   // [1,256,200,200] f32
    const float* boxes = (const float*)d_in[1];   // [1024,4] f32
    float* out = (float*)d_out;                   // [1024,256,7,7] f32

    const size_t tBytes   = (size_t)NG * GSTRIDE * sizeof(float);     // 40.96 MB
    const size_t auxBytes = (size_t)NCHUNK * WC * sizeof(float);      // 5.12 MB
    const int    total    = N_BOX * C_CH * OHp * OWp;
    const int    blocks   = total / 256;

    if (ws_size >= tBytes + auxBytes) {
        float* T2  = (float*)d_ws;
        float* aux = (float*)((char*)d_ws + tBytes);
        transpose_wscan_kernel<<<dim3(H_FM, NG), 256, 0, stream>>>(fm, T2);
        colscan_chunk_kernel<<<dim3(WC / 256, NCHUNK), 256, 0, stream>>>(T2, aux);
        aux_scan_kernel<<<WC / 256, 256, 0, stream>>>(aux);
        add_offsets_kernel<<<(H_FM - CHROWS) * (WC / 4) / 256, 256, 0, stream>>>(T2, aux);
        pool4_kernel<<<N_BOX * NG, 256, 0, stream>>>(T2, boxes, out);
    } else {
        pool_direct_kernel<<<blocks, 256, 0, stream>>>(fm, boxes, out);
    }
}

// Round 5
// 141.428 us; speedup vs baseline: 1.6952x; 1.0262x over previous
//
#include <hip/hip_runtime.h>

#define C_CH  256
#define H_FM  200
#define W_FM  200
#define N_BOX 1024
#define OHp   7
#define OWp   7
#define NG    8                       // channel groups
#define CG    32                      // channels per group
#define WC    (W_FM * C_CH)           // 51200 columns
#define NCHUNK 25                     // h chunks of 8 rows
#define CHROWS 8
#define GSTRIDE (H_FM * W_FM * CG)    // 1,280,000 floats per group slice
#define HSTRIDE (W_FM * CG)           // 6,400 floats per h row (within group)
#define AUXG    (NCHUNK * HSTRIDE)    // 160,000 floats per group aux slice

// ============================================================================
// Layouts:
//   T2[g][h][w][cg]   : w-scanned then h-scanned WITHIN 8-row chunks only.
//   aux2[g][ch][w][cg]: exclusive h-chunk offsets (after aux_scan).
// Final integral image value (1-based r,k):
//   II(r,k)[c] = T2[g][r-1][k-1][cg] + aux2[g][(r-1)>>3][k-1][cg]
// Pool adds the aux term on the fly -> no finalize pass over T2.
// ============================================================================

// ----------------------------------------------------------------------------
// K1: coalesced load -> LDS -> register-serial w-scan -> coalesced transposed
// store into T2 (full w-prefix, h not yet scanned). Block = (h, group g).
// All LDS access patterns conflict-free (33-pad).
// ----------------------------------------------------------------------------
__global__ __launch_bounds__(256) void transpose_wscan_kernel(const float* __restrict__ fm,
                                                              float* __restrict__ T2) {
    __shared__ float tile[W_FM][CG + 1];   // [w][cg]
    __shared__ float tot[8][CG + 1];
    __shared__ float offE[8][CG + 1];
    const int t = threadIdx.x;
    const int h = blockIdx.x;
    const int g = blockIdx.y;
    const int c0 = g * CG;

    // Coalesced load: 32 channel-rows x 200 w = 6400 floats.
    #pragma unroll
    for (int s = 0; s < 25; ++s) {
        int flat = s * 256 + t;            // 0..6399
        int ci = flat / W_FM;
        int w  = flat - ci * W_FM;
        tile[w][ci] = fm[(size_t)(c0 + ci) * (H_FM * W_FM) + (size_t)h * W_FM + w];
    }
    __syncthreads();

    // Register-serial scan: thread (cg, chb) scans w in [chb*25, chb*25+25).
    const int cg  = t & 31;
    const int chb = t >> 5;                // 0..7
    {
        float acc = 0.0f;
        #pragma unroll
        for (int s = 0; s < 25; ++s) {
            acc += tile[chb * 25 + s][cg];
            tile[chb * 25 + s][cg] = acc;
        }
        tot[chb][cg] = acc;
    }
    __syncthreads();

    // Exclusive scan of the 8 w-chunk totals.
    {
        float off = 0.0f;
        #pragma unroll
        for (int k = 0; k < 8; ++k) {
            float v = tot[k][cg];
            if (k < chb) off += v;
        }
        offE[chb][cg] = off;
    }
    __syncthreads();

    // Coalesced store: T2[g][h][w][cg], contiguous 6400-float run.
    float* dst = T2 + (size_t)g * GSTRIDE + (size_t)h * HSTRIDE;
    #pragma unroll
    for (int m = 0; m < 25; ++m) {
        int flat = m * 256 + t;
        int w  = flat >> 5;
        int cc = flat & 31;
        dst[flat] = tile[w][cc] + offE[w / 25][cc];
    }
}

// ----------------------------------------------------------------------------
// K2: h-cumsum per chunk of 8 rows, in place, float4. Writes chunk totals to
// aux2[g][ch][.]. Grid (WC/4/256=50, NCHUNK). Fully coalesced 16 B/lane.
// ----------------------------------------------------------------------------
__global__ __launch_bounds__(256) void colscan_chunk_kernel(float* __restrict__ T2,
                                                            float* __restrict__ aux2) {
    const int q4 = blockIdx.x * 256 + threadIdx.x;    // 0..WC/4-1
    const int ch = blockIdx.y;
    const int g  = q4 / (HSTRIDE / 4);
    const int r4 = q4 - g * (HSTRIDE / 4);
    float4* p = (float4*)T2 + (size_t)g * (GSTRIDE / 4)
                            + (size_t)(ch * CHROWS) * (HSTRIDE / 4) + r4;
    float4 acc = make_float4(0.f, 0.f, 0.f, 0.f);
    #pragma unroll
    for (int k = 0; k < CHROWS; ++k) {
        float4 v = p[(size_t)k * (HSTRIDE / 4)];
        acc.x += v.x; acc.y += v.y; acc.z += v.z; acc.w += v.w;
        p[(size_t)k * (HSTRIDE / 4)] = acc;
    }
    ((float4*)aux2)[(size_t)g * (AUXG / 4) + (size_t)ch * (HSTRIDE / 4) + r4] = acc;
}

// ----------------------------------------------------------------------------
// K3: exclusive scan of the 25 chunk totals, in place, float4.
// ----------------------------------------------------------------------------
__global__ __launch_bounds__(256) void aux_scan_kernel(float* __restrict__ aux2) {
    const int idx = blockIdx.x * 256 + threadIdx.x;   // 0..WC/4-1
    const int g   = idx / (HSTRIDE / 4);
    const int r4  = idx - g * (HSTRIDE / 4);
    float4* p = (float4*)aux2 + (size_t)g * (AUXG / 4) + r4;
    float4 acc = make_float4(0.f, 0.f, 0.f, 0.f);
    #pragma unroll
    for (int ch = 0; ch < NCHUNK; ++ch) {
        float4 v = p[(size_t)ch * (HSTRIDE / 4)];
        p[(size_t)ch * (HSTRIDE / 4)] = acc;
        acc.x += v.x; acc.y += v.y; acc.z += v.z; acc.w += v.w;
    }
}

// ----------------------------------------------------------------------------
// K4: pooling, aux folded in. Block = (box n, group g), blockIdx = n*8+g so
// each XCD re-reads only its own 5.1 MB T2 slice + 0.64 MB aux slice
// (L2-hot). Thread (cg, islot<7): 28 T2 corner loads + 28 aux loads, all
// 128 B coalesced segments. LDS 6.3 KB -> high occupancy. float4 flush.
// ----------------------------------------------------------------------------
__global__ __launch_bounds__(256) void pool5_kernel(const float* __restrict__ T2,
                                                    const float* __restrict__ aux2,
                                                    const float* __restrict__ boxes,
                                                    float* __restrict__ out) {
    __shared__ __align__(16) float lo[CG * 49];
    const int bx = blockIdx.x;
    const int n  = bx >> 3;
    const int g  = bx & 7;
    const int t  = threadIdx.x;
    const int cg = t & 31;
    const int islot = t >> 5;         // 0..7 (7 idle in compute phase)

    const float4 box = ((const float4*)boxes)[n];
    int b0 = (int)floorf(box.x * 0.25f);
    int b1 = (int)floorf(box.y * 0.25f);
    int b2 = (int)floorf(box.z * 0.25f);
    int b3 = (int)floorf(box.w * 0.25f);
    int x1 = min(max(b0, 0), W_FM - 1);
    int y1 = min(max(b1, 0), H_FM - 1);
    int x2 = min(max(b2 + 1, x1 + 1), W_FM);
    int y2 = min(max(b3 + 1, y1 + 1), H_FM);
    int rh = y2 - y1;
    int rw = x2 - x1;

    if (islot < OHp) {
        const int i  = islot;
        const int rt = y1 + (i * rh) / OHp;
        const int rb = y1 + ((i + 1) * rh + OHp - 1) / OHp;
        int colv[2 * OWp];
        #pragma unroll
        for (int j = 0; j < OWp; ++j) {
            colv[j]       = x1 + (j * rw) / OWp;
            colv[OWp + j] = x1 + ((j + 1) * rw + OWp - 1) / OWp;
        }
        const float* base = T2   + (size_t)g * GSTRIDE + cg;
        const float* abase = aux2 + (size_t)g * AUXG   + cg;
        const int ra  = max(rt - 1, 0) * W_FM;          // clamped row offsets
        const int rbm = (rb - 1) * W_FM;                // rb >= 1 always
        const int ca  = (max(rt - 1, 0) >> 3) * W_FM;   // aux chunk rows
        const int cb  = ((rb - 1) >> 3) * W_FM;
        float top[2 * OWp], bot[2 * OWp];
        #pragma unroll
        for (int k = 0; k < 2 * OWp; ++k) {
            const int kk = colv[k];
            const int ka = max(kk - 1, 0);
            float tv = base[(size_t)(ra  + ka) * CG] + abase[(size_t)(ca + ka) * CG];
            float bv = base[(size_t)(rbm + ka) * CG] + abase[(size_t)(cb + ka) * CG];
            top[k] = (rt > 0 && kk > 0) ? tv : 0.0f;   // block-uniform masks
            bot[k] = (kk > 0)           ? bv : 0.0f;
        }
        const float rowspan = (float)(rb - rt);
        #pragma unroll
        for (int j = 0; j < OWp; ++j) {
            float total = (bot[OWp + j] - bot[j]) - (top[OWp + j] - top[j]);
            float area  = rowspan * (float)(colv[OWp + j] - colv[j]);
            lo[cg * 49 + i * OWp + j] = total / area;  // stride 49: conflict-free
        }
    }
    __syncthreads();

    // float4 flush: 392 float4 = 1568 contiguous floats.
    float4* dst4 = (float4*)(out + (size_t)n * (C_CH * 49) + (size_t)g * (CG * 49));
    const float4* lo4 = (const float4*)lo;
    #pragma unroll
    for (int m = 0; m < 2; ++m) {
        int idx = m * 256 + t;
        if (idx < CG * 49 / 4) dst4[idx] = lo4[idx];
    }
}

// ============================================================================
// FALLBACK PATH — used only if workspace is too small.
// ============================================================================
__device__ __forceinline__ void box_edges(const float4 box, int i, int j,
                                          int& rs, int& re, int& cs, int& ce) {
    int b0 = (int)floorf(box.x * 0.25f);
    int b1 = (int)floorf(box.y * 0.25f);
    int b2 = (int)floorf(box.z * 0.25f);
    int b3 = (int)floorf(box.w * 0.25f);
    int x1 = min(max(b0, 0), W_FM - 1);
    int y1 = min(max(b1, 0), H_FM - 1);
    int x2 = min(max(b2 + 1, x1 + 1), W_FM);
    int y2 = min(max(b3 + 1, y1 + 1), H_FM);
    int rh = y2 - y1;
    int rw = x2 - x1;
    rs = y1 + (i * rh) / OHp;
    re = y1 + ((i + 1) * rh + OHp - 1) / OHp;
    cs = x1 + (j * rw) / OWp;
    ce = x1 + ((j + 1) * rw + OWp - 1) / OWp;
}

__global__ __launch_bounds__(256) void pool_direct_kernel(const float* __restrict__ fm,
                                                          const float* __restrict__ boxes,
                                                          float* __restrict__ out) {
    const int idx = blockIdx.x * 256 + threadIdx.x;
    const int j  = idx % OWp;
    const int t1 = idx / OWp;
    const int i  = t1 % OHp;
    const int t2 = t1 / OHp;
    const int c  = t2 % C_CH;
    const int n  = t2 / C_CH;

    const float4 box = ((const float4*)boxes)[n];
    int rs, re, cs, ce;
    box_edges(box, i, j, rs, re, cs, ce);

    const float* base = fm + (size_t)c * (H_FM * W_FM);
    float sum = 0.0f;
    for (int r = rs; r < re; ++r) {
        const float* rowp = base + (size_t)r * W_FM;
        for (int k = cs; k < ce; ++k) sum += rowp[k];
    }
    float area = (float)((re - rs) * (ce - cs));
    out[idx] = sum / area;
}

// ---------------------------------------------------------------------------
extern "C" void kernel_launch(void* const* d_in, const int* in_sizes, int n_in,
                              void* d_out, int out_size, void* d_ws, size_t ws_size,
                              hipStream_t stream) {
    const float* fm    = (const float*)d_in[0];   // [1,256,200,200] f32
    const float* boxes = (const float*)d_in[1];   // [1024,4] f32
    float* out = (float*)d_out;                   // [1024,256,7,7] f32

    const size_t tBytes   = (size_t)NG * GSTRIDE * sizeof(float);     // 40.96 MB
    const size_t auxBytes = (size_t)NG * AUXG * sizeof(float);        // 5.12 MB
    const int    total    = N_BOX * C_CH * OHp * OWp;
    const int    blocks   = total / 256;

    if (ws_size >= tBytes + auxBytes) {
        float* T2   = (float*)d_ws;
        float* aux2 = (float*)((char*)d_ws + tBytes);
        transpose_wscan_kernel<<<dim3(H_FM, NG), 256, 0, stream>>>(fm, T2);
        colscan_chunk_kernel<<<dim3(WC / 4 / 256, NCHUNK), 256, 0, stream>>>(T2, aux2);
        aux_scan_kernel<<<WC / 4 / 256, 256, 0, stream>>>(aux2);
        pool5_kernel<<<N_BOX * NG, 256, 0, stream>>>(T2, aux2, boxes, out);
    } else {
        pool_direct_kernel<<<blocks, 256, 0, stream>>>(fm, boxes, out);
    }
}